// Round 10
// baseline (1254.292 us; speedup 1.0000x reference)
//
#include <hip/hip_runtime.h>

#define NP 131072   // points (= 2^17)
#define DD 128      // dims (GEMM K)
#define KK 256      // clusters (GEMM N)
#define MAXIT 8
#define TOLSQ (1e-4f * 1e-4f)
#define LP 129      // padded LDS sums row stride (129%32==1 -> label spreads banks)

typedef _Float16 half8 __attribute__((ext_vector_type(8)));
typedef float f32x4 __attribute__((ext_vector_type(4)));

// ws re-poisoned 0xAA before every timed call — every field below is written
// before it is read on every kernel_launch.
struct Ws {
    float C[KK * DD];
    float newC[KK * DD];
    float cnorm[KK];
    float shiftsq;
    int done;
    int counts[KK];                            // per-cluster sizes (exact, int)
    alignas(16) float partial[256 * KK * DD];  // per-block partial sums (32 MB)
    // fp16 hi/lo planes, pre-swizzled into MFMA fragment order (16B aligned)
    alignas(16) _Float16 Csh[KK * DD];
    alignas(16) _Float16 Csl[KK * DD];
    alignas(16) _Float16 Xsh[(size_t)NP * DD];
    alignas(16) _Float16 Xsl[(size_t)NP * DD];
};

// C0 = X[init_idx]; zero done flag.  grid: KK x DD
__global__ void k_init(const float* __restrict__ X, const int* __restrict__ idx,
                       float* __restrict__ C, int* __restrict__ done) {
    int k = blockIdx.x, d = threadIdx.x;
    C[k * DD + d] = X[(size_t)idx[k] * DD + d];
    if (k == 0 && d == 0) *done = 0;
}

// Once per call: split X into fp16 hi/lo planes in A-fragment order.
// A-frag (16x16x32 f16): lane L of the wave owning 16-point group g16 at
// k-step ks holds X[g16*16 + (L&15)][ks*32 + (L>>4)*8 + j], j=0..7.
// Flat: Xs[(((g16*4)+ks)*64 + L)*8 + j].  grid: NP*DD/8/256 = 8192 blocks.
__global__ void k_split(const float* __restrict__ X, _Float16* __restrict__ Xh,
                        _Float16* __restrict__ Xl) {
    size_t idx = (size_t)blockIdx.x * 256 + threadIdx.x;  // one per 8 elems
    int lane = idx & 63;
    size_t g16k = idx >> 6;
    size_t point = (g16k >> 2) * 16 + (lane & 15);
    int dim0 = (int)(g16k & 3) * 32 + (lane >> 4) * 8;
    const f32x4* s4 = (const f32x4*)(X + point * DD + dim0);
    f32x4 a = s4[0], b = s4[1];
    half8 h, l;
#pragma unroll
    for (int j = 0; j < 4; j++) {
        _Float16 hi = (_Float16)a[j];
        h[j] = hi; l[j] = (_Float16)(a[j] - (float)hi);
    }
#pragma unroll
    for (int j = 0; j < 4; j++) {
        _Float16 hi = (_Float16)b[j];
        h[4 + j] = hi; l[4 + j] = (_Float16)(b[j] - (float)hi);
    }
    *(half8*)(Xh + idx * 8) = h;
    *(half8*)(Xl + idx * 8) = l;
}

// Initial prep: cnorm + hi/lo B-fragment planes for C0; zero counts.
// B-frag: lane L at (ks, cluster-tile ct) holds C[ct*16+(L&15)][ks*32+(L>>4)*8+j]
// -> flat ((ks*16+ct)*64 + L)*8 + j.  grid: KK x DD
__global__ void k_prep0(const float* __restrict__ C, float* __restrict__ cnorm,
                        _Float16* __restrict__ Ch, _Float16* __restrict__ Cl,
                        int* __restrict__ counts) {
    int k = blockIdx.x, d = threadIdx.x;
    float v = C[k * DD + d];
    _Float16 hi = (_Float16)v;
    int ct = k >> 4, l4 = k & 15, ks = d >> 5, q = (d >> 3) & 3, j = d & 7;
    size_t dst = ((size_t)(ks * 16 + ct) * 64 + (q * 16 + l4)) * 8 + j;
    Ch[dst] = hi;
    Cl[dst] = (_Float16)(v - (float)hi);
    __shared__ float red[DD];
    red[d] = v * v;
    __syncthreads();
    for (int s = DD / 2; s > 0; s >>= 1) {
        if (d < s) red[d] += red[d + s];
        __syncthreads();
    }
    if (d == 0) {
        cnorm[k] = red[0];
        counts[k] = 0;
    }
}

// MFMA assignment + FUSED CLUSTER-SUM. GEMM/argmin is R3 verbatim (its 40us
// floor survived every lever: occupancy/B-location/prefetch/stagger/setprio/
// lean-VALU — ledger closed). New: the scatter+sort+gather sum pipeline
// (~29us/iter, re-reads 64MB of X) is replaced by in-kernel accumulation —
// the A-frags already hold x = hi+lo (err ~2.4e-7 rel). Per round: one
// barrier publishes the round's argmin keys in mbuf; each wave re-loads its
// L1-hot ks=q A-slice, merges labels from the 4 quarters, and ds_add_f32s
// into LDS sums[256][LP=129] (pad: 129%32==1 so distinct labels hit distinct
// banks). End: dump the 128KB block-partial coalesced (no atomics); k_reduce
// folds 256 partials. No second per-round barrier needed: mbuf slots are
// per-round unique and ds_adds commute.
// LDS: 132K sums + 16K mbuf + 1K hist = 149.25 KB (1 block/CU — unchanged;
// the block was already solo-resident at 2 waves/SIMD).
// grid: NP/512 = 256 x 512.
__global__ __launch_bounds__(512, 2) void k_assign(
    const _Float16* __restrict__ Xh, const _Float16* __restrict__ Xl,
    const _Float16* __restrict__ Ch, const _Float16* __restrict__ Cl,
    const float* __restrict__ cnorm, float* __restrict__ outlab,
    int* __restrict__ counts, float* __restrict__ partial,
    float* __restrict__ shiftsq) {
    __shared__ float lsums[KK * LP];             // 132 KB padded accumulator
    __shared__ unsigned long long mbuf[4][512];  // [quarter][local point]
    __shared__ int hist[KK];
    const int tid = threadIdx.x;
    const int wave = tid >> 6;
    const int lane = tid & 63;
    const int l4 = lane & 15, g = lane >> 4;
    const int pgrp = wave >> 2;   // point-group pair (0..1)
    const int q = wave & 3;       // cluster quarter (ct q*4 .. q*4+3)

    if (blockIdx.x == 0 && tid == 0) *shiftsq = 0.0f;
    if (tid < KK) hist[tid] = 0;
    for (int i = tid; i < KK * LP; i += 512) lsums[i] = 0.0f;
    // round-0 barrier (below) orders zeroing before any ds_add.

    // B quarter into registers, permanent. Fragment layout matches k_prep0:
    // flat ((ks*16 + ct)*64 + lane)*8, 16B/lane coalesced.
    half8 Bh[4][4], Bl[4][4];
#pragma unroll
    for (int ks = 0; ks < 4; ks++)
#pragma unroll
        for (int c = 0; c < 4; c++) {
            size_t off = ((size_t)(ks * 16 + q * 4 + c) * 64 + lane) * 8;
            Bh[ks][c] = *(const half8*)(Ch + off);
            Bl[ks][c] = *(const half8*)(Cl + off);
        }

    float cn[4];
#pragma unroll
    for (int c = 0; c < 4; c++) cn[c] = cnorm[(q * 4 + c) * 16 + l4];

    // prologue: A-frags for (round 0, ks 0)
    const int gb = blockIdx.x * 32 + pgrp * 2;
    size_t a0 = ((size_t)(gb * 4) * 64 + lane) * 8;
    size_t a1 = ((size_t)((gb + 1) * 4) * 64 + lane) * 8;
    half8 ah0 = *(const half8*)(Xh + a0), al0 = *(const half8*)(Xl + a0);
    half8 ah1 = *(const half8*)(Xh + a1), al1 = *(const half8*)(Xl + a1);

#pragma unroll 1
    for (int r = 0; r < 8; r++) {
        f32x4 acc[2][4];
#pragma unroll
        for (int pg = 0; pg < 2; pg++)
#pragma unroll
            for (int c = 0; c < 4; c++) acc[pg][c] = (f32x4){0.f, 0.f, 0.f, 0.f};

#pragma unroll
        for (int ks = 0; ks < 4; ks++) {
            // prefetch next flat step's A (clamped re-load on the very last)
            int ns = r * 4 + ks + 1;
            ns = ns > 31 ? 31 : ns;
            const int ng16 = blockIdx.x * 32 + (ns >> 2) * 4 + pgrp * 2;
            const int nks = ns & 3;
            const size_t b0 = ((size_t)(ng16 * 4 + nks) * 64 + lane) * 8;
            const size_t b1 = ((size_t)((ng16 + 1) * 4 + nks) * 64 + lane) * 8;
            half8 nh0 = *(const half8*)(Xh + b0), nl0 = *(const half8*)(Xl + b0);
            half8 nh1 = *(const half8*)(Xh + b1), nl1 = *(const half8*)(Xl + b1);

            // 24 MFMAs; dependent chains (same acc) are 8 issues apart.
#pragma unroll
            for (int c = 0; c < 4; c++) {
                acc[0][c] = __builtin_amdgcn_mfma_f32_16x16x32_f16(al0, Bh[ks][c], acc[0][c], 0, 0, 0);
                acc[1][c] = __builtin_amdgcn_mfma_f32_16x16x32_f16(al1, Bh[ks][c], acc[1][c], 0, 0, 0);
            }
#pragma unroll
            for (int c = 0; c < 4; c++) {
                acc[0][c] = __builtin_amdgcn_mfma_f32_16x16x32_f16(ah0, Bl[ks][c], acc[0][c], 0, 0, 0);
                acc[1][c] = __builtin_amdgcn_mfma_f32_16x16x32_f16(ah1, Bl[ks][c], acc[1][c], 0, 0, 0);
            }
#pragma unroll
            for (int c = 0; c < 4; c++) {
                acc[0][c] = __builtin_amdgcn_mfma_f32_16x16x32_f16(ah0, Bh[ks][c], acc[0][c], 0, 0, 0);
                acc[1][c] = __builtin_amdgcn_mfma_f32_16x16x32_f16(ah1, Bh[ks][c], acc[1][c], 0, 0, 0);
            }
            ah0 = nh0; al0 = nl0; ah1 = nh1; al1 = nl1;
        }

        // Round epilogue: packed argmin over this wave's 64 clusters.
        // Key = (monotone(float) << 32) | cluster; NaN -> -inf beats all.
        unsigned long long best[2][4];
#pragma unroll
        for (int pg = 0; pg < 2; pg++)
#pragma unroll
            for (int rr = 0; rr < 4; rr++) best[pg][rr] = ~0ull;

#pragma unroll
        for (int pg = 0; pg < 2; pg++)
#pragma unroll
            for (int c = 0; c < 4; c++)
#pragma unroll
                for (int rr = 0; rr < 4; rr++) {
                    float s = fmaf(-2.0f, acc[pg][c][rr], cn[c]);
                    if (__builtin_isnan(s)) s = -__builtin_inff();
                    unsigned u = __float_as_uint(s);
                    unsigned m = (u >> 31) ? ~u : (u ^ 0x80000000u);
                    unsigned long long key =
                        ((unsigned long long)m << 32) |
                        (unsigned)((q * 4 + c) * 16 + l4);
                    if (key < best[pg][rr]) best[pg][rr] = key;
                }

        // reduce over the 16 cluster-column lanes (low 4 lane bits)
#pragma unroll
        for (int d = 1; d < 16; d <<= 1)
#pragma unroll
            for (int pg = 0; pg < 2; pg++)
#pragma unroll
                for (int rr = 0; rr < 4; rr++) {
                    unsigned long long o = __shfl_xor(best[pg][rr], d, 64);
                    if (o < best[pg][rr]) best[pg][rr] = o;
                }

        if (l4 == 0) {
#pragma unroll
            for (int pg = 0; pg < 2; pg++)
#pragma unroll
                for (int rr = 0; rr < 4; rr++) {
                    int pl = (r * 4 + pgrp * 2 + pg) * 16 + g * 4 + rr;
                    mbuf[q][pl] = best[pg][rr];
                }
        }

        // ---- fused cluster-sum for round r ----
        // re-issue this wave's ks=q A-slice (L1-hot: read this round) BEFORE
        // the barrier so the latency hides under barrier + mbuf reads.
        const int rg16 = blockIdx.x * 32 + r * 4 + pgrp * 2;
        const size_t s0 = ((size_t)(rg16 * 4 + q) * 64 + lane) * 8;
        const size_t s1 = ((size_t)((rg16 + 1) * 4 + q) * 64 + lane) * 8;
        half8 rh0 = *(const half8*)(Xh + s0), rl0 = *(const half8*)(Xl + s0);
        half8 rh1 = *(const half8*)(Xh + s1), rl1 = *(const half8*)(Xl + s1);

        __syncthreads();  // round-r mbuf slots visible (also orders lsums zero)

        // merge the 4 quarters' keys for this lane's two points (pg=0,1)
        const int plb = (r * 4 + pgrp * 2) * 16 + l4;
        unsigned long long k00 = mbuf[0][plb], k01 = mbuf[1][plb];
        unsigned long long k02 = mbuf[2][plb], k03 = mbuf[3][plb];
        unsigned long long m0 = k00 < k01 ? k00 : k01;
        unsigned long long m0b = k02 < k03 ? k02 : k03;
        int lab0 = (int)((m0 < m0b ? m0 : m0b) & 0xff);
        unsigned long long k10 = mbuf[0][plb + 16], k11 = mbuf[1][plb + 16];
        unsigned long long k12 = mbuf[2][plb + 16], k13 = mbuf[3][plb + 16];
        unsigned long long m1 = k10 < k11 ? k10 : k11;
        unsigned long long m1b = k12 < k13 ? k12 : k13;
        int lab1 = (int)((m1 < m1b ? m1 : m1b) & 0xff);

        const int dbase = q * 32 + g * 8;
        float* r0 = &lsums[lab0 * LP + dbase];
        float* r1 = &lsums[lab1 * LP + dbase];
#pragma unroll
        for (int j = 0; j < 8; j++)
            atomicAdd(&r0[j], (float)rh0[j] + (float)rl0[j]);
#pragma unroll
        for (int j = 0; j < 8; j++)
            atomicAdd(&r1[j], (float)rh1[j] + (float)rl1[j]);
        // no second barrier: next round's mbuf slots are disjoint; ds_adds
        // commute and are drained by the next round's barrier.
    }

    __syncthreads();  // all mbuf writes + ds_adds complete
    {
        unsigned long long k0 = mbuf[0][tid], k1 = mbuf[1][tid];
        unsigned long long k2 = mbuf[2][tid], k3 = mbuf[3][tid];
        unsigned long long ka = k0 < k1 ? k0 : k1;
        unsigned long long kb = k2 < k3 ? k2 : k3;
        unsigned long long k = ka < kb ? ka : kb;
        int point = blockIdx.x * 512 + tid;
        int lbl = (int)(k & 0x1ff);
        outlab[point] = (float)lbl;
        atomicAdd(&hist[lbl], 1);
    }
    __syncthreads();  // all hist adds complete
    if (tid < KK) {
        int h = hist[tid];
        if (h) atomicAdd(&counts[tid], h);
    }

    // dump block-partial (strip pad), coalesced global writes, no atomics
    float* gp = partial + (size_t)blockIdx.x * (KK * DD);
    for (int i = tid; i < KK * DD; i += 512) {
        int k = i >> 7, d = i & 127;
        gp[i] = lsums[k * LP + d];
    }
}

// Fold 256 block-partials -> newC = sum/count (0/0 -> NaN, matching jnp);
// shift^2 block-reduced, one atomic per block. Block = 128 g-entries x
// 2 r-halves (r-split for MLP on the strided column reads; per-r accesses
// are coalesced across threads).  grid: KK*DD/128 = 256 x 256.
__global__ __launch_bounds__(256) void k_reduce(
    const float* __restrict__ partial, const int* __restrict__ counts,
    const float* __restrict__ C, float* __restrict__ newC,
    float* __restrict__ shiftsq) {
    const int t = threadIdx.x;
    const int g = blockIdx.x * 128 + (t & 127);
    const int rh = t >> 7;
    float s = 0.f;
#pragma unroll 8
    for (int r = rh * 128; r < rh * 128 + 128; r++)
        s += partial[(size_t)r * (KK * DD) + g];

    __shared__ float red[256];
    red[t] = s;
    __syncthreads();
    float diff = 0.f;
    if (t < 128) {
        int k = g >> 7;
        float nc = (red[t] + red[t + 128]) / (float)counts[k];
        newC[g] = nc;
        diff = nc - C[g];
    }
    __syncthreads();
    red[t] = diff * diff;  // t>=128 contribute 0
    __syncthreads();
    for (int st = 128; st > 0; st >>= 1) {
        if (t < st) red[t] += red[t + st];
        __syncthreads();
    }
    if (t == 0) atomicAdd(shiftsq, red[0]);
}

// Fused convergence check + centroid update + next-iter prep (cnorm + hi/lo
// planes) + zero counts. NaN shiftsq -> not converged (jnp match).
// Benign done race: all blocks compute the same nd.  grid: KK/2 x 256.
__global__ void k_upprep(const float* __restrict__ newC, float* __restrict__ C,
                         const float* __restrict__ shiftsq, int* __restrict__ done,
                         float* __restrict__ cnorm, _Float16* __restrict__ Ch,
                         _Float16* __restrict__ Cl, int* __restrict__ counts) {
    const int t = threadIdx.x;
    const int k = blockIdx.x * 2 + (t >> 7);
    const int d = t & 127;
    float ss = *shiftsq;
    int nd = (*done != 0) || (ss < TOLSQ);
    float v = nd ? C[k * DD + d] : newC[k * DD + d];
    C[k * DD + d] = v;
    if (blockIdx.x == 0 && t == 0 && nd) *done = 1;
    if (d == 0) counts[k] = 0;

    _Float16 hi = (_Float16)v;
    int ct = k >> 4, l4 = k & 15, ks = d >> 5, q = (d >> 3) & 3, j = d & 7;
    size_t dst = ((size_t)(ks * 16 + ct) * 64 + (q * 16 + l4)) * 8 + j;
    Ch[dst] = hi;
    Cl[dst] = (_Float16)(v - (float)hi);

    __shared__ float red[256];
    red[t] = v * v;
    __syncthreads();
    for (int s = 64; s > 0; s >>= 1) {
        if ((t & 127) < s) red[t] += red[t + s];
        __syncthreads();
    }
    if (d == 0) cnorm[k] = red[t];
}

__global__ void k_final(const float* __restrict__ C, float* __restrict__ out) {
    int i = blockIdx.x * 256 + threadIdx.x;
    out[i] = C[i];
}

extern "C" void kernel_launch(void* const* d_in, const int* in_sizes, int n_in,
                              void* d_out, int out_size, void* d_ws, size_t ws_size,
                              hipStream_t stream) {
    const float* X = (const float*)d_in[0];
    const int* idx = (const int*)d_in[1];
    float* out = (float*)d_out;
    Ws* w = (Ws*)d_ws;

    k_init<<<KK, DD, 0, stream>>>(X, idx, w->C, &w->done);
    k_split<<<(int)((size_t)NP * DD / 8 / 256), 256, 0, stream>>>(X, w->Xsh, w->Xsl);
    k_prep0<<<KK, DD, 0, stream>>>(w->C, w->cnorm, w->Csh, w->Csl, w->counts);

    for (int it = 0; it < MAXIT; it++) {
        k_assign<<<NP / 512, 512, 0, stream>>>(w->Xsh, w->Xsl, w->Csh, w->Csl,
                                               w->cnorm, out, w->counts,
                                               w->partial, &w->shiftsq);
        k_reduce<<<KK * DD / 128, 256, 0, stream>>>(w->partial, w->counts, w->C,
                                                    w->newC, &w->shiftsq);
        k_upprep<<<KK / 2, 256, 0, stream>>>(w->newC, w->C, &w->shiftsq, &w->done,
                                             w->cnorm, w->Csh, w->Csl, w->counts);
    }

    k_final<<<KK * DD / 256, 256, 0, stream>>>(w->C, out + NP);
}

// Round 11
// 635.566 us; speedup vs baseline: 1.9735x; 1.9735x over previous
//
#include <hip/hip_runtime.h>

#define NP 131072   // points (= 2^17, label packs above bit 17)
#define DD 128      // dims (GEMM K)
#define KK 256      // clusters (GEMM N)
#define MAXIT 8
#define TOLSQ (1e-4f * 1e-4f)
#define POSB 128    // positions per k_sum block (128 -> 1024 blocks, 4/CU TLP)
#define UPIPE 8     // gather pipeline depth

typedef _Float16 half8 __attribute__((ext_vector_type(8)));
typedef float f32x4 __attribute__((ext_vector_type(4)));

// ws re-poisoned 0xAA before every timed call — every field below is written
// before it is read on every kernel_launch.
struct Ws {
    float C[KK * DD];
    float newC[KK * DD];
    float cnorm[KK];
    float sums[KK * DD];       // per-cluster coordinate sums (atomic-flushed)
    float shiftsq;
    int done;
    int ilab[NP];              // labels
    int counts[KK];            // per-cluster sizes (exact, int)
    int cursor[KK];            // global reservation cursors (zeroed per iter)
    int ordlab[NP];            // cluster-sorted: point | (label<<17)
    // fp16 hi/lo planes, pre-swizzled into MFMA fragment order (16B aligned)
    alignas(16) _Float16 Csh[KK * DD];
    alignas(16) _Float16 Csl[KK * DD];
    alignas(16) _Float16 Xsh[(size_t)NP * DD];
    alignas(16) _Float16 Xsl[(size_t)NP * DD];
};

// Once per call: split X into fp16 hi/lo planes in A-fragment order.
// A-frag (16x16x32 f16): lane L of the wave owning 16-point group g16 at
// k-step ks holds X[g16*16 + (L&15)][ks*32 + (L>>4)*8 + j], j=0..7.
// Flat: Xs[(((g16*4)+ks)*64 + L)*8 + j].  grid: NP*DD/8/256 = 8192 blocks.
__global__ void k_split(const float* __restrict__ X, _Float16* __restrict__ Xh,
                        _Float16* __restrict__ Xl) {
    size_t idx = (size_t)blockIdx.x * 256 + threadIdx.x;  // one per 8 elems
    int lane = idx & 63;
    size_t g16k = idx >> 6;
    size_t point = (g16k >> 2) * 16 + (lane & 15);
    int dim0 = (int)(g16k & 3) * 32 + (lane >> 4) * 8;
    const f32x4* s4 = (const f32x4*)(X + point * DD + dim0);
    f32x4 a = s4[0], b = s4[1];
    half8 h, l;
#pragma unroll
    for (int j = 0; j < 4; j++) {
        _Float16 hi = (_Float16)a[j];
        h[j] = hi; l[j] = (_Float16)(a[j] - (float)hi);
    }
#pragma unroll
    for (int j = 0; j < 4; j++) {
        _Float16 hi = (_Float16)b[j];
        h[4 + j] = hi; l[4 + j] = (_Float16)(b[j] - (float)hi);
    }
    *(half8*)(Xh + idx * 8) = h;
    *(half8*)(Xl + idx * 8) = l;
}

// Initial prep, with k_init FOLDED IN: gather C0 = X[init_idx] directly,
// write C, cnorm, hi/lo B-fragment planes; zero counts/cursor/done.
// B-frag: lane L at (ks, cluster-tile ct) holds C[ct*16+(L&15)][ks*32+(L>>4)*8+j]
// -> flat ((ks*16+ct)*64 + L)*8 + j.  grid: KK x DD
__global__ void k_prep0(const float* __restrict__ X, const int* __restrict__ idx,
                        float* __restrict__ C, float* __restrict__ cnorm,
                        _Float16* __restrict__ Ch, _Float16* __restrict__ Cl,
                        int* __restrict__ counts, int* __restrict__ cursor,
                        int* __restrict__ done) {
    int k = blockIdx.x, d = threadIdx.x;
    float v = X[(size_t)idx[k] * DD + d];
    C[k * DD + d] = v;
    if (k == 0 && d == 0) *done = 0;
    _Float16 hi = (_Float16)v;
    int ct = k >> 4, l4 = k & 15, ks = d >> 5, q = (d >> 3) & 3, j = d & 7;
    size_t dst = ((size_t)(ks * 16 + ct) * 64 + (q * 16 + l4)) * 8 + j;
    Ch[dst] = hi;
    Cl[dst] = (_Float16)(v - (float)hi);
    __shared__ float red[DD];
    red[d] = v * v;
    __syncthreads();
    for (int s = DD / 2; s > 0; s >>= 1) {
        if (d < s) red[d] += red[d + s];
        __syncthreads();
    }
    if (d == 0) {
        cnorm[k] = red[0];
        counts[k] = 0;
        cursor[k] = 0;
    }
}

// MFMA assignment — R3 VERBATIM (best measured: 40.2us; ledger closed after
// 10 rounds: occupancy 2->4/SIMD, LDS-staged/persistent/register B, prefetch
// depth 1->4, antiphase stagger, setprio, lean-VALU epilogue, fused-sum —
// all neutral or negative. The one load-bearing property: ZERO barriers and
// ZERO ds_reads in the main loop). 8 waves = 2 point-groups x 4 cluster-
// quarters; each wave holds its B quarter (4 ct x 4 ks x hi/lo = 32 half8 =
// 128 VGPR) permanently in registers; 8 rounds x 64 points; A prefetched
// 1 step ahead; cross-quarter argmin merge via mbuf + one end barrier.
// grid: NP/512 = 256 x 512.
__global__ __launch_bounds__(512, 2) void k_assign(
    const _Float16* __restrict__ Xh, const _Float16* __restrict__ Xl,
    const _Float16* __restrict__ Ch, const _Float16* __restrict__ Cl,
    const float* __restrict__ cnorm, float* __restrict__ outlab,
    int* __restrict__ ilab, int* __restrict__ counts,
    float* __restrict__ shiftsq) {
    __shared__ unsigned long long mbuf[4][512];  // [quarter][local point]
    __shared__ int hist[KK];
    const int tid = threadIdx.x;
    const int wave = tid >> 6;
    const int lane = tid & 63;
    const int l4 = lane & 15, g = lane >> 4;
    const int pgrp = wave >> 2;   // point-group pair (0..1)
    const int q = wave & 3;       // cluster quarter (ct q*4 .. q*4+3)

    if (blockIdx.x == 0 && tid == 0) *shiftsq = 0.0f;
    if (tid < KK) hist[tid] = 0;

    // B quarter into registers, permanent. Fragment layout matches k_prep0:
    // flat ((ks*16 + ct)*64 + lane)*8, 16B/lane coalesced.
    half8 Bh[4][4], Bl[4][4];
#pragma unroll
    for (int ks = 0; ks < 4; ks++)
#pragma unroll
        for (int c = 0; c < 4; c++) {
            size_t off = ((size_t)(ks * 16 + q * 4 + c) * 64 + lane) * 8;
            Bh[ks][c] = *(const half8*)(Ch + off);
            Bl[ks][c] = *(const half8*)(Cl + off);
        }

    float cn[4];
#pragma unroll
    for (int c = 0; c < 4; c++) cn[c] = cnorm[(q * 4 + c) * 16 + l4];

    // prologue: A-frags for (round 0, ks 0)
    const int gb = blockIdx.x * 32 + pgrp * 2;
    size_t a0 = ((size_t)(gb * 4) * 64 + lane) * 8;
    size_t a1 = ((size_t)((gb + 1) * 4) * 64 + lane) * 8;
    half8 ah0 = *(const half8*)(Xh + a0), al0 = *(const half8*)(Xl + a0);
    half8 ah1 = *(const half8*)(Xh + a1), al1 = *(const half8*)(Xl + a1);

#pragma unroll 1
    for (int r = 0; r < 8; r++) {
        f32x4 acc[2][4];
#pragma unroll
        for (int pg = 0; pg < 2; pg++)
#pragma unroll
            for (int c = 0; c < 4; c++) acc[pg][c] = (f32x4){0.f, 0.f, 0.f, 0.f};

#pragma unroll
        for (int ks = 0; ks < 4; ks++) {
            // prefetch next flat step's A (clamped re-load on the very last)
            int ns = r * 4 + ks + 1;
            ns = ns > 31 ? 31 : ns;
            const int ng16 = blockIdx.x * 32 + (ns >> 2) * 4 + pgrp * 2;
            const int nks = ns & 3;
            const size_t b0 = ((size_t)(ng16 * 4 + nks) * 64 + lane) * 8;
            const size_t b1 = ((size_t)((ng16 + 1) * 4 + nks) * 64 + lane) * 8;
            half8 nh0 = *(const half8*)(Xh + b0), nl0 = *(const half8*)(Xl + b0);
            half8 nh1 = *(const half8*)(Xh + b1), nl1 = *(const half8*)(Xl + b1);

            // 24 MFMAs; dependent chains (same acc) are 8 issues apart.
#pragma unroll
            for (int c = 0; c < 4; c++) {
                acc[0][c] = __builtin_amdgcn_mfma_f32_16x16x32_f16(al0, Bh[ks][c], acc[0][c], 0, 0, 0);
                acc[1][c] = __builtin_amdgcn_mfma_f32_16x16x32_f16(al1, Bh[ks][c], acc[1][c], 0, 0, 0);
            }
#pragma unroll
            for (int c = 0; c < 4; c++) {
                acc[0][c] = __builtin_amdgcn_mfma_f32_16x16x32_f16(ah0, Bl[ks][c], acc[0][c], 0, 0, 0);
                acc[1][c] = __builtin_amdgcn_mfma_f32_16x16x32_f16(ah1, Bl[ks][c], acc[1][c], 0, 0, 0);
            }
#pragma unroll
            for (int c = 0; c < 4; c++) {
                acc[0][c] = __builtin_amdgcn_mfma_f32_16x16x32_f16(ah0, Bh[ks][c], acc[0][c], 0, 0, 0);
                acc[1][c] = __builtin_amdgcn_mfma_f32_16x16x32_f16(ah1, Bh[ks][c], acc[1][c], 0, 0, 0);
            }
            ah0 = nh0; al0 = nl0; ah1 = nh1; al1 = nl1;
        }

        // Round epilogue: packed argmin over this wave's 64 clusters.
        // Key = (monotone(float) << 32) | cluster; NaN -> -inf beats all.
        unsigned long long best[2][4];
#pragma unroll
        for (int pg = 0; pg < 2; pg++)
#pragma unroll
            for (int rr = 0; rr < 4; rr++) best[pg][rr] = ~0ull;

#pragma unroll
        for (int pg = 0; pg < 2; pg++)
#pragma unroll
            for (int c = 0; c < 4; c++)
#pragma unroll
                for (int rr = 0; rr < 4; rr++) {
                    float s = fmaf(-2.0f, acc[pg][c][rr], cn[c]);
                    if (__builtin_isnan(s)) s = -__builtin_inff();
                    unsigned u = __float_as_uint(s);
                    unsigned m = (u >> 31) ? ~u : (u ^ 0x80000000u);
                    unsigned long long key =
                        ((unsigned long long)m << 32) |
                        (unsigned)((q * 4 + c) * 16 + l4);
                    if (key < best[pg][rr]) best[pg][rr] = key;
                }

        // reduce over the 16 cluster-column lanes (low 4 lane bits)
#pragma unroll
        for (int d = 1; d < 16; d <<= 1)
#pragma unroll
            for (int pg = 0; pg < 2; pg++)
#pragma unroll
                for (int rr = 0; rr < 4; rr++) {
                    unsigned long long o = __shfl_xor(best[pg][rr], d, 64);
                    if (o < best[pg][rr]) best[pg][rr] = o;
                }

        if (l4 == 0) {
#pragma unroll
            for (int pg = 0; pg < 2; pg++)
#pragma unroll
                for (int rr = 0; rr < 4; rr++) {
                    int pl = (r * 4 + pgrp * 2 + pg) * 16 + g * 4 + rr;
                    mbuf[q][pl] = best[pg][rr];
                }
        }
    }

    __syncthreads();  // all mbuf writes + hist zero visible
    {
        unsigned long long k0 = mbuf[0][tid], k1 = mbuf[1][tid];
        unsigned long long k2 = mbuf[2][tid], k3 = mbuf[3][tid];
        unsigned long long ka = k0 < k1 ? k0 : k1;
        unsigned long long kb = k2 < k3 ? k2 : k3;
        unsigned long long k = ka < kb ? ka : kb;
        int point = blockIdx.x * 512 + tid;
        int lbl = (int)(k & 0x1ff);
        outlab[point] = (float)lbl;
        ilab[point] = lbl;
        atomicAdd(&hist[lbl], 1);
    }
    __syncthreads();  // all hist adds complete
    if (tid < KK) {
        int h = hist[tid];
        if (h) atomicAdd(&counts[tid], h);
    }
}

// Counting-sort scatter. Block = 512 points: LDS histogram, redundant prefix
// of global counts, ONE block-aggregated cursor reservation per cluster, then
// rank & write ordlab[pos] = p | (label<<17). Also zeroes sums for k_sum.
// grid: NP/512 = 256 blocks x 256 threads.
__global__ __launch_bounds__(256) void k_scatter(
    const int* __restrict__ ilab, const int* __restrict__ counts,
    int* __restrict__ cursor, int* __restrict__ ordlab,
    float* __restrict__ sums) {
    const int t = threadIdx.x;
    const int b = blockIdx.x;

    // zero sums slice: 256 blocks x 128 floats = KK*DD
    if (t < 128) sums[b * 128 + t] = 0.0f;

    __shared__ int hist[KK];
    __shared__ int pre[KK];
    __shared__ int gbase[KK];
    hist[t] = 0;
    int c = counts[t];
    pre[t] = c;
    __syncthreads();

    const int p0 = b * 512;
    const int la = ilab[p0 + t];
    const int lb = ilab[p0 + 256 + t];
    atomicAdd(&hist[la], 1);
    atomicAdd(&hist[lb], 1);

    // inclusive prefix of counts (Hillis-Steele)
#pragma unroll
    for (int d = 1; d < KK; d <<= 1) {
        int v = (t >= d) ? pre[t - d] : 0;
        __syncthreads();
        pre[t] += v;
        __syncthreads();
    }
    // after these syncs all hist atomics are complete
    int h = hist[t];
    int gb = (pre[t] - c) + (h ? atomicAdd(&cursor[t], h) : 0);
    gbase[t] = gb;
    __syncthreads();
    hist[t] = 0;  // reuse as intra-block rank cursor
    __syncthreads();

    int ra = atomicAdd(&hist[la], 1);
    ordlab[gbase[la] + ra] = (p0 + t) | (la << 17);
    int rb = atomicAdd(&hist[lb], 1);
    ordlab[gbase[lb] + rb] = (p0 + 256 + t) | (lb << 17);
}

// Streaming segmented sum over the cluster-sorted position list.
// Position-balanced (immune to cluster-size skew). Thread = (dim d, parity h);
// U-deep double-buffered row gathers; register accumulator flushed on label
// change (wave-uniform branch) via coalesced global atomicAdd — few per block.
// POSB=128 -> 1024 blocks -> 4 blocks/CU = 4 waves/SIMD of TLP on the
// latency-bound L3 gather (was 2 at POSB=256).
// grid: NP/POSB = 1024 blocks x 256 threads.
__global__ __launch_bounds__(256) void k_sum(
    const float* __restrict__ X, const int* __restrict__ ordlab,
    float* __restrict__ sums) {
    const int t = threadIdx.x;
    const int d = t & 127, h = t >> 7;

    __shared__ int sol[POSB];
    if (t < POSB) sol[t] = ordlab[blockIdx.x * POSB + t];
    __syncthreads();

    const int PP = POSB / 2;  // positions per parity
    float xv[UPIPE], xn[UPIPE];
#pragma unroll
    for (int u = 0; u < UPIPE; u++)
        xv[u] = X[(size_t)(sol[2 * u + h] & 0x1ffff) * DD + d];

    float acc = 0.0f;
    int cur = sol[h] >> 17;

    for (int jb = 0; jb < PP; jb += UPIPE) {
        // issue next batch's gathers (tail clamped to a harmless valid index)
#pragma unroll
        for (int u = 0; u < UPIPE; u++) {
            int nj = jb + u + UPIPE;
            int o = sol[2 * (nj < PP ? nj : PP - 1) + h];
            xn[u] = X[(size_t)(o & 0x1ffff) * DD + d];
        }
        // consume current batch
#pragma unroll
        for (int u = 0; u < UPIPE; u++) {
            int l = sol[2 * (jb + u) + h] >> 17;
            if (l != cur) {
                atomicAdd(&sums[cur * DD + d], acc);
                acc = 0.0f;
                cur = l;
            }
            acc += xv[u];
        }
#pragma unroll
        for (int u = 0; u < UPIPE; u++) xv[u] = xn[u];
    }
    atomicAdd(&sums[cur * DD + d], acc);
}

// newC = sums/counts (0/0 -> NaN, matching jnp); shift^2 block-reduced,
// one atomic per block.  grid: KK*DD/256 x 256
__global__ void k_reduce(const float* __restrict__ sums, const int* __restrict__ counts,
                         const float* __restrict__ C, float* __restrict__ newC,
                         float* __restrict__ shiftsq) {
    const int g = blockIdx.x * 256 + threadIdx.x;
    const int k = g >> 7;
    const int t = threadIdx.x;

    float nc = sums[g] / (float)counts[k];
    newC[g] = nc;
    float diff = nc - C[g];

    __shared__ float red[256];
    red[t] = diff * diff;
    __syncthreads();
    for (int st = 128; st > 0; st >>= 1) {
        if (t < st) red[t] += red[t + st];
        __syncthreads();
    }
    if (t == 0) atomicAdd(shiftsq, red[0]);
}

// Fused convergence check + centroid update + next-iter prep (cnorm + hi/lo
// planes) + zero counts/cursor. NaN shiftsq -> not converged (jnp match).
// Benign done race: all blocks compute the same nd. On the LAST iteration,
// also writes the final centroids to the output (k_final folded in).
// grid: KK/2 x 256.
__global__ void k_upprep(const float* __restrict__ newC, float* __restrict__ C,
                         const float* __restrict__ shiftsq, int* __restrict__ done,
                         float* __restrict__ cnorm, _Float16* __restrict__ Ch,
                         _Float16* __restrict__ Cl, int* __restrict__ counts,
                         int* __restrict__ cursor, float* __restrict__ outC) {
    const int t = threadIdx.x;
    const int k = blockIdx.x * 2 + (t >> 7);
    const int d = t & 127;
    float ss = *shiftsq;
    int nd = (*done != 0) || (ss < TOLSQ);
    float v = nd ? C[k * DD + d] : newC[k * DD + d];
    C[k * DD + d] = v;
    if (outC) outC[k * DD + d] = v;
    if (blockIdx.x == 0 && t == 0 && nd) *done = 1;
    if (d == 0) {
        counts[k] = 0;
        cursor[k] = 0;
    }

    _Float16 hi = (_Float16)v;
    int ct = k >> 4, l4 = k & 15, ks = d >> 5, q = (d >> 3) & 3, j = d & 7;
    size_t dst = ((size_t)(ks * 16 + ct) * 64 + (q * 16 + l4)) * 8 + j;
    Ch[dst] = hi;
    Cl[dst] = (_Float16)(v - (float)hi);

    __shared__ float red[256];
    red[t] = v * v;
    __syncthreads();
    for (int s = 64; s > 0; s >>= 1) {
        if ((t & 127) < s) red[t] += red[t + s];
        __syncthreads();
    }
    if (d == 0) cnorm[k] = red[t];
}

extern "C" void kernel_launch(void* const* d_in, const int* in_sizes, int n_in,
                              void* d_out, int out_size, void* d_ws, size_t ws_size,
                              hipStream_t stream) {
    const float* X = (const float*)d_in[0];
    const int* idx = (const int*)d_in[1];
    float* out = (float*)d_out;
    Ws* w = (Ws*)d_ws;

    k_split<<<(int)((size_t)NP * DD / 8 / 256), 256, 0, stream>>>(X, w->Xsh, w->Xsl);
    k_prep0<<<KK, DD, 0, stream>>>(X, idx, w->C, w->cnorm, w->Csh, w->Csl,
                                   w->counts, w->cursor, &w->done);

    for (int it = 0; it < MAXIT; it++) {
        k_assign<<<NP / 512, 512, 0, stream>>>(w->Xsh, w->Xsl, w->Csh, w->Csl,
                                               w->cnorm, out, w->ilab, w->counts,
                                               &w->shiftsq);
        k_scatter<<<NP / 512, 256, 0, stream>>>(w->ilab, w->counts, w->cursor,
                                                w->ordlab, w->sums);
        k_sum<<<NP / POSB, 256, 0, stream>>>(X, w->ordlab, w->sums);
        k_reduce<<<KK * DD / 256, 256, 0, stream>>>(w->sums, w->counts, w->C,
                                                    w->newC, &w->shiftsq);
        k_upprep<<<KK / 2, 256, 0, stream>>>(w->newC, w->C, &w->shiftsq, &w->done,
                                             w->cnorm, w->Csh, w->Csl, w->counts,
                                             w->cursor,
                                             (it == MAXIT - 1) ? out + NP : nullptr);
    }
}